// Round 7
// baseline (353.530 us; speedup 1.0000x reference)
//
#include <hip/hip_runtime.h>
#include <hip/hip_bf16.h>
#include <math.h>

#define N_NODES 100000
#define C 256
#define NB 64
#define H1D 128
#define NG 128
#define BN_EPS 1e-5f

#define BLKN 16                           // rows per wave-subtile (halved: 2x waves)
#define NSUB (N_NODES / BLKN)             // 6250 wave-tasks, exact
#define WPB 2                             // waves per block
#define NBLK1 (NSUB / WPB)                // 3125 blocks, exact (no tail)
#define NPART NBLK1                       // pbn rows (one per BLOCK, merged in LDS)

// per-graph record: XC[256] | XS[256] | BS[256] (b*4+{CV,SV,CC,CS}) | cnt
#define GREC 769

// ws layout (float offsets)
#define OFF_GSUMS 0
#define OFF_BNSUM (NG * GREC)            // 98432
#define OFF_BNSQ  (OFF_BNSUM + 256)      // 98688
#define ZERO_FLOATS (OFF_BNSQ + 256)     // 98944 floats zeroed in k0
#define OFF_HMEAN ZERO_FLOATS            // 98944
#define OFF_WT1   (OFF_HMEAN + NG * C)   // +32768
#define OFF_WT2   (OFF_WT1 + 16896)
#define OFF_CSN   (OFF_WT2 + 4352)       // N*128 bf16 = 6.4M floats
#define OFF_PBN   (OFF_CSN + N_NODES * 64)   // NPART x 512 fp32 (6.4 MB)

#define WT1_LD 264   // bf16 stride of Wt1 in global (16B-aligned rows)
#define WT2_LD 136
// h1s LDS stride = WT2_LD (136 bf16): row shift 272B = 68 banks -> spread

typedef __attribute__((ext_vector_type(8))) short bf16x8;
typedef __attribute__((ext_vector_type(4))) float f32x4;

__device__ __forceinline__ float bf2f(__hip_bfloat16 h) { return __bfloat162float(h); }

__device__ __forceinline__ float fast_tanh(float y) {
    // exact identity, fast exp (v_exp); y bounded (~|y|<6) in this net
    float e = __expf(2.f * y);
    return 1.f - 2.f / (e + 1.f);
}
__device__ __forceinline__ float fast_gelu(float v) {
    // tanh-form GELU, max abs err ~1.5e-3 vs exact-erf (threshold 0.11)
    float u = 0.7978845608f * (v + 0.044715f * v * v * v);
    return 0.5f * v * (1.f + fast_tanh(u));
}

__device__ __forceinline__ bf16x8 pack8(float4 a, float4 b) {
    union { bf16x8 v; __hip_bfloat16 h[8]; } u;
    u.h[0] = __float2bfloat16(a.x); u.h[1] = __float2bfloat16(a.y);
    u.h[2] = __float2bfloat16(a.z); u.h[3] = __float2bfloat16(a.w);
    u.h[4] = __float2bfloat16(b.x); u.h[5] = __float2bfloat16(b.y);
    u.h[6] = __float2bfloat16(b.z); u.h[7] = __float2bfloat16(b.w);
    return u.v;
}

// ---------------------------------------------------------------------------
// K0: zero the stats region (replaces the hipMemsetAsync dispatch) and
//     transpose+convert weights to bf16 [out_ch][in_ch] layout for MFMA B-frags
// ---------------------------------------------------------------------------
__global__ __launch_bounds__(256)
void k0_prep(const float* __restrict__ W1, const float* __restrict__ W2,
             float* __restrict__ ws,
             __hip_bfloat16* __restrict__ Wt1, __hip_bfloat16* __restrict__ Wt2)
{
    const int t0 = threadIdx.x + blockIdx.x * 256;
    const int stride = gridDim.x * 256;          // 131072
    for (int i = t0; i < ZERO_FLOATS; i += stride)
        ws[i] = 0.f;
    for (int i = t0; i < 128 * 256; i += stride) {
        int n = i >> 8, k = i & 255;
        Wt1[n * WT1_LD + k] = __float2bfloat16(W1[k * 128 + n]);
    }
    for (int i = t0; i < 64 * 128; i += stride) {
        int n = i >> 7, k = i & 127;
        Wt2[n * WT2_LD + k] = __float2bfloat16(W2[k * 64 + n]);
    }
}

// ---------------------------------------------------------------------------
// K1: 16-row subtile per wave, 2 independent waves per 128-thread block,
// 6250 waves total (24.4/CU of work -- round-6 showed the 3125-wave grid was
// the occupancy limit, not packing). Zero barriers in the work path; ONE
// __syncthreads at the very end merges the two waves' BN partials so pbn
// stays one row per block (same footprint as before).
//   Per wave: GEMM1(16x256@256x128, A-frags straight from global) -> GELU ->
//   h1s LDS -> GEMM2(16x128@128x64) -> tanh/sincos -> csn LDS -> csng global;
//   Phase D re-reads x (L1-hot, 16KB/wave) for per-graph stats (atomics per
//   graph segment) + BN partials.
// ---------------------------------------------------------------------------
__global__ __launch_bounds__(128, 6)
void k1_wave(const float* __restrict__ x,
             const int* __restrict__ batch,
             const __hip_bfloat16* __restrict__ Wt1g,
             const float* __restrict__ b1,
             const __hip_bfloat16* __restrict__ Wt2g,
             const float* __restrict__ b2,
             float* __restrict__ gsums,
             float* __restrict__ pbn,
             __hip_bfloat16* __restrict__ csng)
{
    __shared__ __hip_bfloat16 h1s2[WPB][BLKN][WT2_LD];   // 2 x 4352 B
    __shared__ int gsh2[WPB][BLKN];                      // 2 x 64 B
    __shared__ float pbs[WPB][512];                      // 4096 B -> 12928 B total

    const int t = threadIdx.x;
    const int wv = t >> 6;                // wave 0..1 (independent tasks)
    const int l = t & 63;
    const int lo = l & 15, quad = l >> 4;
    const int wid = blockIdx.x * WPB + wv;   // 0..6249, exact
    const int n0 = wid * BLKN;

    auto h1s = h1s2[wv];
    auto csn = (__hip_bfloat16 (*)[132])&h1s2[wv][0][0];  // [2c]=cos,[2c+1]=sin
    int* gsh = gsh2[wv];

    if (l < BLKN) gsh[l] = batch[n0 + l];

    // ---- GEMM1: h1 = x[16,256] @ W1[256,128]; 1 Mtile x 8 Ntiles x 8 K ----
    f32x4 acc1[8];
    #pragma unroll
    for (int nt = 0; nt < 8; ++nt) acc1[nt] = (f32x4)0.f;

    const float* xr0 = x + (size_t)(n0 + lo) * C + quad * 8;
    const short* w1row = (const short*)Wt1g + lo * WT1_LD + quad * 8;
    #pragma unroll
    for (int k = 0; k < 8; ++k) {
        float4 u00 = *(const float4*)(xr0 + k * 32);
        float4 u01 = *(const float4*)(xr0 + k * 32 + 4);
        bf16x8 a0 = pack8(u00, u01);
        #pragma unroll
        for (int nt = 0; nt < 8; ++nt) {
            bf16x8 bB = *(const bf16x8*)(w1row + nt * 16 * WT1_LD + k * 32);
            acc1[nt] = __builtin_amdgcn_mfma_f32_16x16x32_bf16(a0, bB, acc1[nt], 0, 0, 0);
        }
    }

    // ---- bias + fast GELU -> h1s (row = quad*4+r, col = nt*16+lo) ----
    #pragma unroll
    for (int nt = 0; nt < 8; ++nt) {
        const float bb = b1[nt * 16 + lo];
        #pragma unroll
        for (int r = 0; r < 4; ++r) {
            float v = fast_gelu(acc1[nt][r] + bb);
            h1s[quad * 4 + r][nt * 16 + lo] = __float2bfloat16(v);
        }
    }

    // ---- GEMM2: ang = h1[16,128] @ W2[128,64]; 1 Mtile x 4 Ntiles x 4 K ----
    f32x4 acc2[4];
    #pragma unroll
    for (int nt = 0; nt < 4; ++nt) acc2[nt] = (f32x4)0.f;
    const short* w2row = (const short*)Wt2g + lo * WT2_LD + quad * 8;
    #pragma unroll
    for (int k = 0; k < 4; ++k) {
        bf16x8 af0 = *(const bf16x8*)&h1s[lo][k * 32 + quad * 8];
        #pragma unroll
        for (int nt = 0; nt < 4; ++nt) {
            bf16x8 bB = *(const bf16x8*)(w2row + nt * 16 * WT2_LD + k * 32);
            acc2[nt] = __builtin_amdgcn_mfma_f32_16x16x32_bf16(af0, bB, acc2[nt], 0, 0, 0);
        }
    }

    // ---- fast tanh -> hw sincos -> interleaved csn (aliases h1s; same-wave
    //      DS ordering guarantees all h1s reads above complete first) ----
    #pragma unroll
    for (int nt = 0; nt < 4; ++nt) {
        const int col = nt * 16 + lo;
        const float bb = b2[col];
        #pragma unroll
        for (int r = 0; r < 4; ++r) {
            float a = fast_tanh(acc2[nt][r] + bb);
            union { unsigned int u; __hip_bfloat16 h[2]; } p;
            p.h[0] = __float2bfloat16(__cosf(a));
            p.h[1] = __float2bfloat16(__sinf(a));
            *(unsigned int*)&csn[quad * 4 + r][2 * col] = p.u;
        }
    }

    // ---- coalesced global write of interleaved cos/sin (8B per lane) ----
    #pragma unroll
    for (int m = 0; m < 8; ++m) {
        int idx = l + m * 64;             // 0..511 : 16 rows x 32 qwords
        int row = idx >> 5;
        int q = idx & 31;
        uint2 v = *(const uint2*)&csn[row][q * 4];
        *(uint2*)(csng + (size_t)(n0 + row) * 128 + q * 4) = v;
    }

    // ---- Phase D: per-graph stats; lane = bundle l, channels 4l..4l+3 ----
    const int c0 = 4 * l;
    float xc0 = 0.f, xc1 = 0.f, xc2 = 0.f, xc3 = 0.f;
    float xs0 = 0.f, xs1 = 0.f, xs2 = 0.f, xs3 = 0.f;
    float xm0 = 0.f, xm1 = 0.f, xm2 = 0.f, xm3 = 0.f;
    float xq0 = 0.f, xq1 = 0.f, xq2 = 0.f, xq3 = 0.f;
    float stc = 0.f, sts = 0.f, stcc = 0.f, stcs = 0.f, rcnt = 0.f;
    int gprev = -1;

#define FLUSH_G(gidx) do {                                            \
        float* rec = gsums + (size_t)(gidx) * GREC;                   \
        atomicAdd(&rec[c0 + 0], xc0); atomicAdd(&rec[c0 + 1], xc1);   \
        atomicAdd(&rec[c0 + 2], xc2); atomicAdd(&rec[c0 + 3], xc3);   \
        atomicAdd(&rec[256 + c0 + 0], xs0); atomicAdd(&rec[256 + c0 + 1], xs1); \
        atomicAdd(&rec[256 + c0 + 2], xs2); atomicAdd(&rec[256 + c0 + 3], xs3); \
        atomicAdd(&rec[512 + c0 + 0], stc); atomicAdd(&rec[512 + c0 + 1], sts); \
        atomicAdd(&rec[512 + c0 + 2], stcc); atomicAdd(&rec[512 + c0 + 3], stcs); \
        if (l == 0) atomicAdd(&rec[768], rcnt);                       \
    } while (0)

    #pragma unroll 8
    for (int r = 0; r < BLKN; ++r) {
        const int g = gsh[r];
        if (g != gprev) {                 // wave-uniform branch
            if (gprev >= 0) FLUSH_G(gprev);
            xc0 = xc1 = xc2 = xc3 = 0.f;
            xs0 = xs1 = xs2 = xs3 = 0.f;
            stc = sts = stcc = stcs = 0.f;
            rcnt = 0.f;
            gprev = g;
        }
        const float4 xv = *(const float4*)(x + (size_t)(n0 + r) * C + c0);
        union { unsigned int u; __hip_bfloat16 h[2]; } cs;
        cs.u = *(const unsigned int*)&csn[r][2 * l];
        const float cv = bf2f(cs.h[0]);
        const float sv = bf2f(cs.h[1]);
        xc0 += xv.x * cv; xc1 += xv.y * cv; xc2 += xv.z * cv; xc3 += xv.w * cv;
        xs0 += xv.x * sv; xs1 += xv.y * sv; xs2 += xv.z * sv; xs3 += xv.w * sv;
        xm0 += xv.x; xm1 += xv.y; xm2 += xv.z; xm3 += xv.w;
        xq0 += xv.x * xv.x; xq1 += xv.y * xv.y; xq2 += xv.z * xv.z; xq3 += xv.w * xv.w;
        stc += cv; sts += sv; stcc += cv * cv; stcs += cv * sv;
        rcnt += 1.f;
    }
    if (gprev >= 0) FLUSH_G(gprev);
#undef FLUSH_G

    // ---- BN partials: stage per-wave in LDS, merge once per block ----
    {
        float4 m4; m4.x = xm0; m4.y = xm1; m4.z = xm2; m4.w = xm3;
        float4 q4; q4.x = xq0; q4.y = xq1; q4.z = xq2; q4.w = xq3;
        *(float4*)&pbs[wv][c0] = m4;
        *(float4*)&pbs[wv][256 + c0] = q4;
    }
    __syncthreads();                      // the ONLY barrier; both waves exact
    {
        const int i4 = 4 * t;             // t 0..127 -> covers 512 floats
        float4 s0 = *(const float4*)&pbs[0][i4];
        float4 s1 = *(const float4*)&pbs[1][i4];
        float4 o;
        o.x = s0.x + s1.x; o.y = s0.y + s1.y;
        o.z = s0.z + s1.z; o.w = s0.w + s1.w;
        *(float4*)&pbn[(size_t)blockIdx.x * 512 + i4] = o;
    }
}

// ---------------------------------------------------------------------------
// K2: prologue: block g reduces a contiguous r-chunk of pbn over ALL channels
//     (coalesced wave reads), one atomicAdd per channel per block.
//     Then per graph: reconstruct rotated pool sums, hmean = (grot@lin_w)/cnt+b;
//     add closed-form BN contributions of o = x + R^T hmean to bnsum/bnsq.
// ---------------------------------------------------------------------------
__global__ __launch_bounds__(256)
void k2_hmean_stats(const float* __restrict__ gsums,
                    const float* __restrict__ pbn,
                    const float* __restrict__ lin_w, const float* __restrict__ lin_b,
                    float* __restrict__ hmean,
                    float* __restrict__ bnsum, float* __restrict__ bnsq)
{
    __shared__ float xc[C], xsv[C], bs4[C], grot[C], hm[C];
    __shared__ float cnt_sh;
    const int g = blockIdx.x;
    const int t = threadIdx.x;

    {
        const int chunk = (NPART + NG - 1) / NG;   // 25
        const int r0 = g * chunk;
        const int r1 = (r0 + chunk < NPART) ? (r0 + chunk) : NPART;
        if (r0 < r1) {
            float a0 = 0.f, a1 = 0.f;
            for (int r = r0; r < r1; ++r) {
                a0 += pbn[(size_t)r * 512 + t];
                a1 += pbn[(size_t)r * 512 + 256 + t];
            }
            atomicAdd(&bnsum[t], a0);
            atomicAdd(&bnsq[t], a1);
        }
    }

    const float* rec = gsums + (size_t)g * GREC;
    xc[t]  = rec[t];
    xsv[t] = rec[256 + t];
    bs4[t] = rec[512 + t];
    if (t == 0) cnt_sh = rec[768];
    __syncthreads();

    const int b = t >> 2, idx2 = t & 3, i2 = idx2 >> 1;
    // rotated pool sum: c0=4b+f pairs with c1=4b+2+f
    grot[t] = (i2 == 0) ? (xc[t] - xsv[t + 2]) : (xsv[t - 2] + xc[t]);
    __syncthreads();

    float a0 = 0.f, a1 = 0.f, a2 = 0.f, a3 = 0.f;
    #pragma unroll 4
    for (int k = 0; k < C; k += 4) {
        a0 += grot[k + 0] * lin_w[(size_t)(k + 0) * C + t];
        a1 += grot[k + 1] * lin_w[(size_t)(k + 1) * C + t];
        a2 += grot[k + 2] * lin_w[(size_t)(k + 2) * C + t];
        a3 += grot[k + 3] * lin_w[(size_t)(k + 3) * C + t];
    }
    const float cnt = cnt_sh;
    const float hv = (cnt > 0.f) ? ((a0 + a1 + a2 + a3) / cnt + lin_b[t]) : 0.f;
    hm[t] = hv;
    hmean[g * C + t] = hv;
    __syncthreads();

    if (cnt > 0.f) {
        const int f = idx2 & 1;
        const float h0 = hm[4 * b + f];
        const float h1 = hm[4 * b + 2 + f];
        const float CV = bs4[4 * b + 0], SV = bs4[4 * b + 1];
        const float CC = bs4[4 * b + 2], CS = bs4[4 * b + 3];
        const float SS = cnt - CC;       // cv^2+sv^2 = 1 (bf16 eps negligible)
        float sumc, sqc;
        if (i2 == 0) {
            sumc = h0 * CV + h1 * SV;
            sqc  = 2.f * (h0 * xc[t] + h1 * xsv[t])
                 + h0 * h0 * CC + 2.f * h0 * h1 * CS + h1 * h1 * SS;
        } else {
            sumc = -h0 * SV + h1 * CV;
            sqc  = 2.f * (-h0 * xsv[t] + h1 * xc[t])
                 + h0 * h0 * SS - 2.f * h0 * h1 * CS + h1 * h1 * CC;
        }
        atomicAdd(&bnsum[t], sumc);
        atomicAdd(&bnsq[t], sqc);
    }
}

// ---------------------------------------------------------------------------
// K4: o = x + R^T hmean[batch[n]], normalized, single output pass.
// ---------------------------------------------------------------------------
__global__ __launch_bounds__(256, 4)
void k4_fused(const float* __restrict__ x,
              const int* __restrict__ batch,
              const __hip_bfloat16* __restrict__ csng,
              const float* __restrict__ hmean,
              const float* __restrict__ bnsum, const float* __restrict__ bnsq,
              const float* __restrict__ gamma, const float* __restrict__ beta,
              float* __restrict__ out)
{
    __shared__ float mul_s[C], add_s[C];
    const int t = threadIdx.x;
    {
        const float inv_n = 1.0f / (float)N_NODES;
        const float mu = bnsum[t] * inv_n;
        const float var = bnsq[t] * inv_n - mu * mu;
        const float inv = rsqrtf(var + BN_EPS);
        const float m = gamma[t] * inv;
        mul_s[t] = m;
        add_s[t] = beta[t] - mu * m;
    }
    __syncthreads();
    const int s = t >> 6;
    const int cg4 = t & 63;
    const float4 mm = *(const float4*)&mul_s[cg4 * 4];
    const float4 aa = *(const float4*)&add_s[cg4 * 4];

    for (int base = blockIdx.x * 4; base < N_NODES; base += gridDim.x * 4) {
        const int n = base + s;
        if (n < N_NODES) {
            const int g = batch[n];
            const float4 hm = *(const float4*)(hmean + (size_t)g * C + cg4 * 4);
            union { unsigned int u; __hip_bfloat16 h[2]; } cs;
            cs.u = *(const unsigned int*)(csng + (size_t)n * 128 + cg4 * 2);
            const float cv = bf2f(cs.h[0]);
            const float sv = bf2f(cs.h[1]);
            const float4 xv = *(const float4*)(x + (size_t)n * C + cg4 * 4);
            float4 o;
            o.x = (xv.x + cv * hm.x + sv * hm.z) * mm.x + aa.x;
            o.y = (xv.y + cv * hm.y + sv * hm.w) * mm.y + aa.y;
            o.z = (xv.z - sv * hm.x + cv * hm.z) * mm.z + aa.z;
            o.w = (xv.w - sv * hm.y + cv * hm.w) * mm.w + aa.w;
            *(float4*)(out + (size_t)n * C + cg4 * 4) = o;
        }
    }
}

// ---------------------------------------------------------------------------
extern "C" void kernel_launch(void* const* d_in, const int* in_sizes, int n_in,
                              void* d_out, int out_size, void* d_ws, size_t ws_size,
                              hipStream_t stream)
{
    const float* x      = (const float*)d_in[0];
    // d_in[1] = edge_index (unused, num_gnn == 0)
    const int* batch    = (const int*)d_in[2];
    const float* W1     = (const float*)d_in[3];
    const float* b1     = (const float*)d_in[4];
    const float* W2     = (const float*)d_in[5];
    const float* b2     = (const float*)d_in[6];
    const float* lin_w  = (const float*)d_in[7];
    const float* lin_b  = (const float*)d_in[8];
    const float* gamma  = (const float*)d_in[9];
    const float* beta   = (const float*)d_in[10];

    float* ws    = (float*)d_ws;
    float* gsums = ws + OFF_GSUMS;
    float* bnsum = ws + OFF_BNSUM;
    float* bnsq  = ws + OFF_BNSQ;
    float* hmean = ws + OFF_HMEAN;
    __hip_bfloat16* Wt1  = (__hip_bfloat16*)(ws + OFF_WT1);
    __hip_bfloat16* Wt2  = (__hip_bfloat16*)(ws + OFF_WT2);
    __hip_bfloat16* csng = (__hip_bfloat16*)(ws + OFF_CSN);
    float* pbn   = ws + OFF_PBN;
    float* out   = (float*)d_out;

    k0_prep<<<512, 256, 0, stream>>>(W1, W2, ws, Wt1, Wt2);
    k1_wave<<<NBLK1, 128, 0, stream>>>(x, batch, Wt1, b1, Wt2, b2,
                                       gsums, pbn, csng);
    k2_hmean_stats<<<NG, 256, 0, stream>>>(gsums, pbn, lin_w, lin_b, hmean, bnsum, bnsq);
    k4_fused<<<2048, 256, 0, stream>>>(x, batch, csng, hmean, bnsum, bnsq,
                                       gamma, beta, out);
}